// Round 15
// baseline (33.851 us; speedup 1.0000x reference)
//
#include <hip/hip_runtime.h>

#define HW       16384                  // 128*128
#define NCLASS   121

// d_out layout (flat f32, return order: pred, m_mask, disappear, appear)
#define OFF_PRED 0
#define OFF_MASK (8 * 3 * HW)                    // 393216
#define OFF_DIS  (OFF_MASK + 8 * NCLASS * HW)    // 16252928
#define OFF_APP  (OFF_DIS + 8 * HW)              // 16384000

#define SENT 100000.0f           // OOB sentinel: all scatter targets rejected

typedef float nfloat4 __attribute__((ext_vector_type(4)));
typedef float nfloat2 __attribute__((ext_vector_type(2)));

__device__ __forceinline__ float hatf(float u) { return fmaxf(0.f, 1.f - fabsf(u)); }
__device__ __forceinline__ void nt4(float* p, float a, float b, float c, float d) {
    nfloat4 v; v.x = a; v.y = b; v.z = c; v.w = d;
    __builtin_nontemporal_store(v, (nfloat4*)p);
}

// One block = one (batch, 4-row tile). Does EVERYTHING for its tile:
// m_mask (121 ch, NT stream issued first = the latency hider), seg (LDS
// scatter over 24 halo rows), dis/app, pred (LDS scatter, 3 ch). 256 blocks.
__global__ __launch_bounds__(256) void k_all(const float* __restrict__ motion,
                                             const float* __restrict__ im_input,
                                             float* __restrict__ out) {
    __shared__ float2 smot[24 * 128];   // motion rows y0-10 .. y0+13 (24 KB)
    __shared__ float  sseg[14 * 128];   // seg rows y0-5 .. y0+8 (7 KB)
    __shared__ float  spred[3 * 4 * 128]; // (6 KB)
    int tid = threadIdx.x;
    int blk = blockIdx.x;
    int b   = blk >> 5;
    int y0  = (blk & 31) << 2;

    const float* motx = motion + (size_t)(b * 2) * HW;
    const float* moty = motx + HW;
    const float* imb  = im_input + (size_t)(b * 6 + 3) * HW;

    // ---- prefetch: motion 24 rows (12 px/thread) ----
    float rmx[12], rmy[12];
    #pragma unroll
    for (int it = 0; it < 12; ++it) {
        int idx = tid + it * 256;
        int sy  = y0 - 10 + (idx >> 7);
        int sx  = idx & 127;
        bool ok = (sy >= 0) && (sy < 128);
        int s   = (ok ? sy : 0) * 128 + sx;
        float mx = motx[s], my = moty[s];
        rmx[it] = ok ? mx : SENT;
        rmy[it] = ok ? my : SENT;
    }
    // ---- prefetch: im 14 rows x 3 ch (7 px/thread each) ----
    float pim0[7], pim1[7], pim2[7];
    #pragma unroll
    for (int it = 0; it < 7; ++it) {
        int idx = tid + it * 256;
        int sy  = y0 - 5 + (idx >> 7);
        int sx  = idx & 127;
        bool ok = (sy >= 0) && (sy < 128);
        int s   = (ok ? sy : 0) * 128 + sx;
        float a = imb[s], bb = imb[HW + s], c = imb[2 * HW + s];
        pim0[it] = ok ? a : 0.f;
        pim1[it] = ok ? bb : 0.f;
        pim2[it] = ok ? c : 0.f;
    }

    // stage motion to LDS; zero accumulators
    #pragma unroll
    for (int it = 0; it < 12; ++it)
        smot[tid + it * 256] = make_float2(rmx[it], rmy[it]);
    #pragma unroll
    for (int i = tid; i < 14 * 128; i += 256) sseg[i] = 0.f;
    #pragma unroll
    for (int i = tid; i < 3 * 4 * 128; i += 256) spred[i] = 0.f;
    __syncthreads();

    // ---- Phase A: m_mask NT store stream (issued first, drains in bg) ----
    {
        int half = tid >> 7;             // 0: kb 0..5, 1: kb 6..10
        int cell = tid & 127;
        int mly  = cell >> 5;            // 0..3
        int mx4  = (cell & 31) << 2;
        float2 m0 = smot[(10 + mly) * 128 + mx4 + 0];
        float2 m1 = smot[(10 + mly) * 128 + mx4 + 1];
        float2 m2 = smot[(10 + mly) * 128 + mx4 + 2];
        float2 m3 = smot[(10 + mly) * 128 + mx4 + 3];
        float av0[11], av1[11], av2[11], av3[11];
        #pragma unroll
        for (int ka = 0; ka < 11; ++ka) {
            float kao = (float)(ka - 5);
            av0[ka] = hatf(m0.x - kao);
            av1[ka] = hatf(m1.x - kao);
            av2[ka] = hatf(m2.x - kao);
            av3[ka] = hatf(m3.x - kao);
        }
        int kb0 = half ? 6 : 0;
        int nkb = half ? 5 : 6;
        float* mm = out + OFF_MASK + (size_t)(b * NCLASS) * HW + (y0 + mly) * 128 + mx4;
        #pragma unroll
        for (int kk = 0; kk < 6; ++kk) {
            if (kk < nkb) {
                int kb = kb0 + kk;
                float kbo = (float)(kb - 5);
                float b0 = hatf(m0.y - kbo), b1 = hatf(m1.y - kbo);
                float b2 = hatf(m2.y - kbo), b3 = hatf(m3.y - kbo);
                #pragma unroll
                for (int ka = 0; ka < 11; ++ka) {
                    nt4(mm + (size_t)(kb * 11 + ka) * HW,
                        b0 * av0[ka], b1 * av1[ka], b2 * av2[ka], b3 * av3[ka]);
                }
            }
        }
    }

    // ---- Phase B: seg scatter (24 source rows -> 14 seg rows) ----
    #pragma unroll
    for (int it = 0; it < 12; ++it) {
        int idx = tid + it * 256;
        int sy  = y0 - 10 + (idx >> 7);
        int sx  = idx & 127;
        float mx = rmx[it], my = rmy[it];
        float flx = floorf(mx), fly = floorf(my);
        float fa = mx - flx, fb = my - fly;
        int ia = (int)flx + 5, ib = (int)fly + 5;
        float wa0 = 1.f - fa, wa1 = fa, wb0 = 1.f - fb, wb1 = fb;
        #pragma unroll
        for (int j = 0; j < 2; ++j) {
            int ty = sy - (ib + j) + 5;
            if (ty < y0 - 5 || ty >= y0 + 9) continue;
            float wb = j ? wb1 : wb0;
            #pragma unroll
            for (int i = 0; i < 2; ++i) {
                int tx = sx - (ia + i) + 5;
                if (tx < 0 || tx >= 128) continue;
                atomicAdd(&sseg[(ty - (y0 - 5)) * 128 + tx], wb * (i ? wa1 : wa0));
            }
        }
    }
    __syncthreads();

    // ---- Phase C: dis/app NT stores (central rows) + sc in regs ----
    float scv[7];
    #pragma unroll
    for (int it = 0; it < 7; ++it) {
        int idx = tid + it * 256;        // sseg row rr = idx>>7 (0..13)
        float v   = sseg[idx];
        float dis = fmaxf(v - 1.f, 0.f);
        scv[it] = 1.f - dis;
        int rr = idx >> 7;
        if (rr >= 5 && rr < 9) {
            int p = b * HW + (y0 + rr - 5) * 128 + (idx & 127);
            __builtin_nontemporal_store(dis, out + OFF_DIS + p);
            __builtin_nontemporal_store(fmaxf(1.f - v, 0.f), out + OFF_APP + p);
        }
    }

    // ---- Phase D: pred scatter (14 source rows -> central 4 rows, 3 ch) ----
    #pragma unroll
    for (int it = 0; it < 7; ++it) {
        int idx = tid + it * 256;
        int rr  = idx >> 7;
        int sx  = idx & 127;
        int sy  = y0 - 5 + rr;
        float2 m = smot[(rr + 5) * 128 + sx];
        float iv0 = pim0[it] * scv[it];
        float iv1 = pim1[it] * scv[it];
        float iv2 = pim2[it] * scv[it];
        float flx = floorf(m.x), fly = floorf(m.y);
        float fa = m.x - flx, fb = m.y - fly;
        int ia = (int)flx + 5, ib = (int)fly + 5;
        float wa0 = 1.f - fa, wa1 = fa, wb0 = 1.f - fb, wb1 = fb;
        #pragma unroll
        for (int j = 0; j < 2; ++j) {
            int ty = sy - (ib + j) + 5;
            if (ty < y0 || ty >= y0 + 4) continue;
            float wb = j ? wb1 : wb0;
            #pragma unroll
            for (int i = 0; i < 2; ++i) {
                int tx = sx - (ia + i) + 5;
                if (tx < 0 || tx >= 128) continue;
                float w = wb * (i ? wa1 : wa0);
                int tr = ty - y0;
                atomicAdd(&spred[(0 * 4 + tr) * 128 + tx], w * iv0);
                atomicAdd(&spred[(1 * 4 + tr) * 128 + tx], w * iv1);
                atomicAdd(&spred[(2 * 4 + tr) * 128 + tx], w * iv2);
            }
        }
    }
    __syncthreads();

    // ---- Phase E: pred stores ----
    {
        int p2 = tid * 2;
        int ly = p2 >> 7;
        int x  = p2 & 127;
        float* predb = out + OFF_PRED + (size_t)(b * 3) * HW + (y0 + ly) * 128 + x;
        #pragma unroll
        for (int ch = 0; ch < 3; ++ch) {
            nfloat2 v;
            v.x = spred[(ch * 4 + ly) * 128 + x];
            v.y = spred[(ch * 4 + ly) * 128 + x + 1];
            __builtin_nontemporal_store(v, (nfloat2*)(predb + (size_t)ch * HW));
        }
    }
}

extern "C" void kernel_launch(void* const* d_in, const int* in_sizes, int n_in,
                              void* d_out, int out_size, void* d_ws, size_t ws_size,
                              hipStream_t stream) {
    const float* im_input = (const float*)d_in[0];   // (8, 6, 128, 128)
    const float* motion   = (const float*)d_in[1];   // (8, 2, 128, 128)
    // d_in[2] = m_kernel: identity by construction, unused.
    float* out = (float*)d_out;

    k_all<<<dim3(256), dim3(256), 0, stream>>>(motion, im_input, out);
}

// Round 16
// 23.585 us; speedup vs baseline: 1.4353x; 1.4353x over previous
//
#include <hip/hip_runtime.h>

#define HW       16384                  // 128*128
#define NCLASS   121

// d_out layout (flat f32, return order: pred, m_mask, disappear, appear)
#define OFF_PRED 0
#define OFF_MASK (8 * 3 * HW)                    // 393216
#define OFF_DIS  (OFF_MASK + 8 * NCLASS * HW)    // 16252928
#define OFF_APP  (OFF_DIS + 8 * HW)              // 16384000

#define SENT 100000.0f           // OOB sentinel: all scatter targets rejected

typedef float nfloat4 __attribute__((ext_vector_type(4)));

__device__ __forceinline__ float hatf(float u) { return fmaxf(0.f, 1.f - fabsf(u)); }
__device__ __forceinline__ void nt4(float* p, float a, float b, float c, float d) {
    nfloat4 v; v.x = a; v.y = b; v.z = c; v.w = d;
    __builtin_nontemporal_store(v, (nfloat4*)p);
}

// L1: seg for one row (128x1 tile). 1024 blocks = 8 batches x 128 rows.
// Sources: 11 rows [y0-5, y0+5]; LDS scatter; write dis/app for the row.
__global__ __launch_bounds__(256) void k_seg(const float* __restrict__ motion,
                                             float* __restrict__ out) {
    __shared__ float sseg[128];
    int tid = threadIdx.x;
    int blk = blockIdx.x;               // 0..1023
    int b   = blk >> 7;
    int y0  = blk & 127;

    const float* motx = motion + (size_t)(b * 2) * HW;
    const float* moty = motx + HW;

    float mxv[6], myv[6];
    #pragma unroll
    for (int it = 0; it < 6; ++it) {
        int idx = tid + it * 256;            // 0..1535; valid < 1408
        int sy  = y0 - 5 + (idx >> 7);
        int sx  = idx & 127;
        bool ok = (idx < 1408) && (sy >= 0) && (sy < 128);
        int s   = (ok ? sy : 0) * 128 + sx;
        float a = motx[s], bb = moty[s];
        mxv[it] = ok ? a : SENT;
        myv[it] = ok ? bb : SENT;
    }

    if (tid < 128) sseg[tid] = 0.f;
    __syncthreads();

    #pragma unroll
    for (int it = 0; it < 6; ++it) {
        int idx = tid + it * 256;
        int sy  = y0 - 5 + (idx >> 7);
        int sx  = idx & 127;
        float mx = mxv[it], my = myv[it];
        float flx = floorf(mx), fly = floorf(my);
        float fa = mx - flx, fb = my - fly;
        int ia = (int)flx + 5, ib = (int)fly + 5;
        float wa0 = 1.f - fa, wa1 = fa, wb0 = 1.f - fb, wb1 = fb;
        #pragma unroll
        for (int j = 0; j < 2; ++j) {
            int ty = sy - (ib + j) + 5;
            if (ty != y0) continue;
            float wb = j ? wb1 : wb0;
            #pragma unroll
            for (int i = 0; i < 2; ++i) {
                int tx = sx - (ia + i) + 5;
                if (tx < 0 || tx >= 128) continue;
                atomicAdd(&sseg[tx], wb * (i ? wa1 : wa0));
            }
        }
    }
    __syncthreads();

    if (tid < 128) {
        float v = sseg[tid];
        int p = b * HW + y0 * 128 + tid;
        out[OFF_DIS + p] = fmaxf(v - 1.f, 0.f);   // normal stores: re-read by L2
        out[OFF_APP + p] = fmaxf(1.f - v, 0.f);
    }
}

// L2: uniform blocks. 1536 = 3 channels x (8 batches x 64 two-row tiles).
// Each block: (a) NT-store ~10 m_mask channels over its OWN 2 rows (channel
// range by slot = c*4 + threadQuarter), (b) pred scatter for channel c of the
// tile from 12 prefetched source rows, (c) pred store. Self-hiding, balanced.
__global__ __launch_bounds__(256) void k_predmask(const float* __restrict__ motion,
                                                  const float* __restrict__ im_input,
                                                  float* __restrict__ out) {
    __shared__ float spred[2 * 128];    // 1 KB
    int tid = threadIdx.x;
    int blk = blockIdx.x;
    int c   = blk % 3;
    int t   = blk / 3;                   // 0..511
    int b   = t >> 6;
    int y0  = (t & 63) << 1;

    const float* motx = motion + (size_t)(b * 2) * HW;
    const float* moty = motx + HW;
    const float* imc  = im_input + (size_t)(b * 6 + 3 + c) * HW;
    const float* disb = out + OFF_DIS + (size_t)b * HW;

    // central motion for mask stores: this thread's 4 px (cell covers 2x128)
    int cell = tid & 63;
    int mly  = cell >> 5;                // 0..1
    int mx4  = (cell & 31) << 2;
    int gC   = (y0 + mly) * 128 + mx4;
    float4 cmx = *(const float4*)(motx + gC);
    float4 cmy = *(const float4*)(moty + gC);

    // pred prefetch: 12 source rows [y0-5, y0+7), 6 px/thread, 4 arrays
    float mxv[6], myv[6], imv[6], dsv[6];
    #pragma unroll
    for (int it = 0; it < 6; ++it) {
        int idx = tid + it * 256;        // 0..1535
        int sy  = y0 - 5 + (idx >> 7);
        int sx  = idx & 127;
        bool ok = (sy >= 0) && (sy < 128);
        int s   = (ok ? sy : 0) * 128 + sx;
        float a = motx[s], bb = moty[s], cc = imc[s], dd = disb[s];
        mxv[it] = ok ? a : SENT;
        myv[it] = ok ? bb : SENT;
        imv[it] = ok ? cc : 0.f;
        dsv[it] = ok ? dd : 0.f;
    }

    spred[tid] = 0.f;
    __syncthreads();

    // ---- mask NT store stream: slot s0 = c*4 + quarter, ch in [s0*121/12, (s0+1)*121/12)
    {
        int s0  = c * 4 + (tid >> 6);
        int ch0 = (s0 * 121) / 12;
        int ch1 = ((s0 + 1) * 121) / 12;
        float* mmB = out + OFF_MASK + (size_t)(b * NCLASS) * HW + gC;
        for (int ch = ch0; ch < ch1; ++ch) {
            int kb = ch / 11;
            int ka = ch - kb * 11;
            float kao = (float)(ka - 5), kbo = (float)(kb - 5);
            nt4(mmB + (size_t)ch * HW,
                hatf(cmy.x - kbo) * hatf(cmx.x - kao),
                hatf(cmy.y - kbo) * hatf(cmx.y - kao),
                hatf(cmy.z - kbo) * hatf(cmx.z - kao),
                hatf(cmy.w - kbo) * hatf(cmx.w - kao));
        }
    }

    // ---- pred scatter into LDS (targets: 2 central rows) ----
    #pragma unroll
    for (int it = 0; it < 6; ++it) {
        int idx = tid + it * 256;
        int sy  = y0 - 5 + (idx >> 7);
        int sx  = idx & 127;
        float mx = mxv[it], my = myv[it];
        float iv = imv[it] * (1.f - dsv[it]);
        float flx = floorf(mx), fly = floorf(my);
        float fa = mx - flx, fb = my - fly;
        int ia = (int)flx + 5, ib = (int)fly + 5;
        float wa0 = 1.f - fa, wa1 = fa, wb0 = 1.f - fb, wb1 = fb;
        #pragma unroll
        for (int j = 0; j < 2; ++j) {
            int ty = sy - (ib + j) + 5;
            if (ty < y0 || ty >= y0 + 2) continue;
            float wb = j ? wb1 : wb0;
            #pragma unroll
            for (int i = 0; i < 2; ++i) {
                int tx = sx - (ia + i) + 5;
                if (tx < 0 || tx >= 128) continue;
                atomicAdd(&spred[(ty - y0) * 128 + tx], wb * (i ? wa1 : wa0) * iv);
            }
        }
    }
    __syncthreads();

    // ---- pred store: 256 px, 1 px/thread ----
    {
        int ly = tid >> 7;
        int x  = tid & 127;
        __builtin_nontemporal_store(
            spred[tid],
            out + OFF_PRED + (size_t)(b * 3 + c) * HW + (y0 + ly) * 128 + x);
    }
}

extern "C" void kernel_launch(void* const* d_in, const int* in_sizes, int n_in,
                              void* d_out, int out_size, void* d_ws, size_t ws_size,
                              hipStream_t stream) {
    const float* im_input = (const float*)d_in[0];   // (8, 6, 128, 128)
    const float* motion   = (const float*)d_in[1];   // (8, 2, 128, 128)
    // d_in[2] = m_kernel: identity by construction, unused.
    float* out = (float*)d_out;

    k_seg<<<dim3(1024), dim3(256), 0, stream>>>(motion, out);
    k_predmask<<<dim3(1536), dim3(256), 0, stream>>>(motion, im_input, out);
}

// Round 17
// 21.646 us; speedup vs baseline: 1.5639x; 1.0896x over previous
//
#include <hip/hip_runtime.h>

#define HW       16384                  // 128*128
#define NCLASS   121

// d_out layout (flat f32, return order: pred, m_mask, disappear, appear)
#define OFF_PRED 0
#define OFF_MASK (8 * 3 * HW)                    // 393216
#define OFF_DIS  (OFF_MASK + 8 * NCLASS * HW)    // 16252928
#define OFF_APP  (OFF_DIS + 8 * HW)              // 16384000

#define NSEGBLK  256             // k_seg: per batch, 32 row-tiles (128x4)
#define NPREDBLK 768             // fused: 3 channels x 256 tiles (128x4), FIRST
#define NMASKBLK (8 * 16 * 11)   // 1408: per batch, 16 row-tiles (128x8), 11 kb

#define SENT 100000.0f           // OOB sentinel: floor->100000, all targets rejected

typedef float nfloat4 __attribute__((ext_vector_type(4)));

__device__ __forceinline__ float hatf(float u) { return fmaxf(0.f, 1.f - fabsf(u)); }

__device__ __forceinline__ void nt_store4(float* p, float a, float b, float c, float d) {
    nfloat4 nv; nv.x = a; nv.y = b; nv.z = c; nv.w = d;
    __builtin_nontemporal_store(nv, (nfloat4*)p);
}

// K1: seg scatter in LDS for a 128x4 tile -> disappear/appear writes.
// Prefetch all guarded loads; asm memory barrier pins them as a real batch
// (without it the compiler sinks loads to uses: VGPR=28, serial latency chain).
__global__ __launch_bounds__(256) void k_seg(const float* __restrict__ motion,
                                             float* __restrict__ out) {
    __shared__ float sseg[4 * 128];     // 2 KB
    int blk = blockIdx.x;               // 0..255
    int b   = blk >> 5;
    int y0  = (blk & 31) << 2;
    int tid = threadIdx.x;

    const float* motx = motion + (size_t)(b * 2) * HW;
    const float* moty = motx + HW;

    float mxv[7], myv[7];
    #pragma unroll
    for (int it = 0; it < 7; ++it) {
        int idx = tid + it * 256;            // 0..1791 -> 14 source rows
        int sy  = y0 - 5 + (idx >> 7);
        int sx  = idx & 127;
        bool ok = (sy >= 0) && (sy < 128);
        int s   = (ok ? sy : 0) * 128 + sx;  // safe fallback address
        float mx = motx[s];
        float my = moty[s];
        mxv[it] = ok ? mx : SENT;
        myv[it] = ok ? my : SENT;
    }
    asm volatile("" ::: "memory");           // force all loads issued & live here

    ((float2*)sseg)[tid] = make_float2(0.f, 0.f);
    __syncthreads();

    #pragma unroll
    for (int it = 0; it < 7; ++it) {
        int idx = tid + it * 256;
        int sy  = y0 - 5 + (idx >> 7);
        int sx  = idx & 127;
        float mx = mxv[it], my = myv[it];
        float flx = floorf(mx), fly = floorf(my);
        float fa = mx - flx, fb = my - fly;
        int ia = (int)flx + 5, ib = (int)fly + 5;
        float wa0 = 1.f - fa, wa1 = fa;
        float wb0 = 1.f - fb, wb1 = fb;
        #pragma unroll
        for (int j = 0; j < 2; ++j) {
            int ty = sy - (ib + j) + 5;
            if (ty < y0 || ty >= y0 + 4) continue;
            float wb = j ? wb1 : wb0;
            #pragma unroll
            for (int i = 0; i < 2; ++i) {
                int tx = sx - (ia + i) + 5;
                if (tx < 0 || tx >= 128) continue;
                atomicAdd(&sseg[(ty - y0) * 128 + tx], wb * (i ? wa1 : wa0));
            }
        }
    }
    __syncthreads();

    int p2 = tid * 2;
    int ly = p2 >> 7;
    int x  = p2 & 127;
    float2 s2 = *(float2*)&sseg[ly * 128 + x];
    float2 d2, a2;
    d2.x = fmaxf(s2.x - 1.f, 0.f); a2.x = fmaxf(1.f - s2.x, 0.f);
    d2.y = fmaxf(s2.y - 1.f, 0.f); a2.y = fmaxf(1.f - s2.y, 0.f);
    int p = b * HW + (y0 + ly) * 128 + x;
    *(float2*)(out + OFF_DIS + p) = d2;
    *(float2*)(out + OFF_APP + p) = a2;
}

// K2 (fused): blk < NPREDBLK -> pred role, ONE channel per block (true batched
// prefetch via asm barrier, dispatched first); blk >= NPREDBLK -> mask role
// (NT float4 stores, write-BW-bound).
__global__ __launch_bounds__(256) void k_maskpred(const float* __restrict__ motion,
                                                  const float* __restrict__ im_input,
                                                  float* __restrict__ out) {
    __shared__ float spred[4 * 128];    // 2 KB (pred role only)
    int tid = threadIdx.x;
    int blk = blockIdx.x;

    if (blk < NPREDBLK) {
        // ---- pred tile 128x4, channel c ----
        int c  = blk >> 8;               // 0..2
        int t  = blk & 255;
        int b  = t >> 5;
        int y0 = (t & 31) << 2;
        const float* motx = motion + (size_t)(b * 2) * HW;
        const float* moty = motx + HW;
        const float* imc  = im_input + (size_t)(b * 6 + 3 + c) * HW;
        const float* disb = out + OFF_DIS + (size_t)b * HW;

        float mxv[7], myv[7], imv[7], dsv[7];
        #pragma unroll
        for (int it = 0; it < 7; ++it) {
            int idx = tid + it * 256;        // 0..1791 -> 14 source rows
            int sy  = y0 - 5 + (idx >> 7);
            int sx  = idx & 127;
            bool ok = (sy >= 0) && (sy < 128);
            int s   = (ok ? sy : 0) * 128 + sx;
            float mx = motx[s];
            float my = moty[s];
            float im = imc[s];
            float ds = disb[s];
            mxv[it] = ok ? mx : SENT;
            myv[it] = ok ? my : SENT;
            imv[it] = ok ? im : 0.f;
            dsv[it] = ds;
        }
        asm volatile("" ::: "memory");       // force all loads issued & live here

        ((float2*)spred)[tid] = make_float2(0.f, 0.f);
        __syncthreads();

        #pragma unroll
        for (int it = 0; it < 7; ++it) {
            int idx = tid + it * 256;
            int sy  = y0 - 5 + (idx >> 7);
            int sx  = idx & 127;
            float mx = mxv[it], my = myv[it];
            float iv = imv[it] * (1.f - dsv[it]);
            float flx = floorf(mx), fly = floorf(my);
            float fa = mx - flx, fb = my - fly;
            int ia = (int)flx + 5, ib = (int)fly + 5;
            float wa0 = 1.f - fa, wa1 = fa;
            float wb0 = 1.f - fb, wb1 = fb;
            #pragma unroll
            for (int j = 0; j < 2; ++j) {
                int ty = sy - (ib + j) + 5;
                if (ty < y0 || ty >= y0 + 4) continue;
                float wb = j ? wb1 : wb0;
                #pragma unroll
                for (int i = 0; i < 2; ++i) {
                    int tx = sx - (ia + i) + 5;
                    if (tx < 0 || tx >= 128) continue;
                    atomicAdd(&spred[(ty - y0) * 128 + tx], wb * (i ? wa1 : wa0) * iv);
                }
            }
        }
        __syncthreads();

        // store 4 rows x 128 of channel c: 2 px/thread
        int p2 = tid * 2;
        int ly = p2 >> 7;
        int x  = p2 & 127;
        float2 v = *(float2*)&spred[ly * 128 + x];
        float* predb = out + OFF_PRED + (size_t)(b * 3 + c) * HW + (y0 + ly) * 128 + x;
        *(float2*)predb = v;
    } else {
        // ---- mask role: write m_mask channel-row kb over a 128x8 tile ----
        int mb = blk - NPREDBLK;         // 0..1407
        int kb = mb % 11;
        int tl = mb / 11;                // 0..127
        int b  = tl >> 4;
        int y0 = (tl & 15) << 3;
        const float* motx = motion + (size_t)(b * 2) * HW;
        const float* moty = motx + HW;

        int ly = tid >> 5;               // 0..7
        int x4 = (tid & 31) << 2;        // 0,4,...,124
        int g  = (y0 + ly) * 128 + x4;
        float4 mx = *(const float4*)(motx + g);
        float4 my = *(const float4*)(moty + g);
        float kbo = (float)(kb - 5);
        float4 bv;
        bv.x = hatf(my.x - kbo); bv.y = hatf(my.y - kbo);
        bv.z = hatf(my.z - kbo); bv.w = hatf(my.w - kbo);
        float* mm = out + OFF_MASK + ((size_t)(b * NCLASS + kb * 11)) * HW + g;
        #pragma unroll
        for (int ka = 0; ka < 11; ++ka) {
            float kao = (float)(ka - 5);
            nt_store4(mm + (size_t)ka * HW,
                      bv.x * hatf(mx.x - kao),
                      bv.y * hatf(mx.y - kao),
                      bv.z * hatf(mx.z - kao),
                      bv.w * hatf(mx.w - kao));
        }
    }
}

extern "C" void kernel_launch(void* const* d_in, const int* in_sizes, int n_in,
                              void* d_out, int out_size, void* d_ws, size_t ws_size,
                              hipStream_t stream) {
    const float* im_input = (const float*)d_in[0];   // (8, 6, 128, 128)
    const float* motion   = (const float*)d_in[1];   // (8, 2, 128, 128)
    // d_in[2] = m_kernel: identity by construction, unused.
    float* out = (float*)d_out;

    k_seg<<<dim3(NSEGBLK), dim3(256), 0, stream>>>(motion, out);
    k_maskpred<<<dim3(NPREDBLK + NMASKBLK), dim3(256), 0, stream>>>(motion, im_input, out);
}